// Round 18
// baseline (191.049 us; speedup 1.0000x reference)
//
#include <hip/hip_runtime.h>
#include <hip/hip_bf16.h>
#include <cstdint>
#include <cstddef>

#define NTOK 32768
#define DIN 512
#define EDIM_ 256
#define HID 1024
#define NEXP 4

typedef __attribute__((ext_vector_type(8))) short short8;
typedef __attribute__((ext_vector_type(16))) float f32x16;

// ---- workspace layout (bytes) ----
#define OFF_COUNTS 0
#define OFF_GVAL   256
#define OFF_PERM   (OFF_GVAL + 131072)
#define OFF_PART   (OFF_PERM + 524288)
#define OFF_WB1    (OFF_PART + 40960)
#define OFF_WB2    (OFF_WB1 + 4194304)

__device__ __forceinline__ unsigned short f2bf(float f) {
  unsigned u = __float_as_uint(f);
  u = (u + 0x7fffu + ((u >> 16) & 1u)) >> 16;
  return (unsigned short)u;
}

__device__ __forceinline__ f32x16 mfma32(short8 a, short8 b, f32x16 c) {
  return __builtin_amdgcn_mfma_f32_32x32x16_bf16(a, b, c, 0, 0, 0);
}

__device__ __forceinline__ short8 pack8(float4 f0, float4 f1) {
  short8 v;
  v[0] = (short)f2bf(f0.x); v[1] = (short)f2bf(f0.y);
  v[2] = (short)f2bf(f0.z); v[3] = (short)f2bf(f0.w);
  v[4] = (short)f2bf(f1.x); v[5] = (short)f2bf(f1.y);
  v[6] = (short)f2bf(f1.z); v[7] = (short)f2bf(f1.w);
  return v;
}

// ---------------- router + W pack (R17-validated) ----------------
__global__ __launch_bounds__(256) void router_kernel(const float* __restrict__ x,
                                                     const float* __restrict__ emb,
                                                     const float* __restrict__ rw,
                                                     float* __restrict__ gval,
                                                     unsigned* __restrict__ counts,
                                                     unsigned* __restrict__ perm,
                                                     double* __restrict__ partials,
                                                     const float* __restrict__ w1,
                                                     const float* __restrict__ w2,
                                                     char* __restrict__ pw1,
                                                     char* __restrict__ pw2) {
  __shared__ float lbuf[32][132];
  __shared__ double vals[64][5];
  __shared__ int sgid[64];
  const int t = threadIdx.x;
  const int wave = t >> 6, lane = t & 63;
  const int l31 = lane & 31, lh = lane >> 5;

  float4 rwe[4], rwx[8];
#pragma unroll
  for (int i = 0; i < 4; ++i) rwe[i] = *(const float4*)(rw + (lane * 4 + i) * 4);
#pragma unroll
  for (int i = 0; i < 8; ++i) rwx[i] = *(const float4*)(rw + (256 + lane * 8 + i) * 4);

#pragma unroll
  for (int m = 0; m < 2; ++m) {
    const unsigned r = blockIdx.x;
    const unsigned e = r >> 7;
    unsigned nb, k8, stride;
    const float* srcb;
    if (m == 0) { nb = (r >> 2) & 31u; k8 = r & 3u; stride = 512;
      srcb = w1 + ((size_t)e << 19) + (size_t)nb * 32 * 512 + k8 * 128; }
    else        { nb = (r >> 3) & 15u; k8 = r & 7u; stride = 1024;
      srcb = w2 + ((size_t)e << 19) + (size_t)nb * 32 * 1024 + k8 * 128; }
    {
      const int row = t >> 3, coff = (t & 7) * 16;
      const float* s = srcb + (size_t)row * stride + coff;
      float4 f0 = *(const float4*)(s), f1 = *(const float4*)(s + 4);
      float4 f2 = *(const float4*)(s + 8), f3 = *(const float4*)(s + 12);
      *(float4*)&lbuf[row][coff] = f0;  *(float4*)&lbuf[row][coff + 4] = f1;
      *(float4*)&lbuf[row][coff + 8] = f2; *(float4*)&lbuf[row][coff + 12] = f3;
    }
    __syncthreads();
#pragma unroll
    for (int pass = 0; pass < 2; ++pass) {
      const int u = pass * 4 + (t >> 6);
      float4 f0 = *(const float4*)&lbuf[l31][u * 16 + lh * 8];
      float4 f1 = *(const float4*)&lbuf[l31][u * 16 + lh * 8 + 4];
      short8 v = pack8(f0, f1);
      size_t unit;
      char* dst;
      if (m == 0) { unit = ((size_t)(e * 32 + nb) * 32) + k8 * 8 + u; dst = pw1; }
      else        { unit = ((size_t)(e * 16 + nb) * 64) + k8 * 8 + u; dst = pw2; }
      *(short8*)(dst + (unit << 10) + lane * 16) = v;
    }
    __syncthreads();
  }

  const int tkb = blockIdx.x * 64 + wave * 16;
  float4 e4 = *(const float4*)(emb + (size_t)tkb * EDIM_ + lane * 4);
  float4 x0 = *(const float4*)(x + (size_t)tkb * DIN + lane * 8);
  float4 x1 = *(const float4*)(x + (size_t)tkb * DIN + lane * 8 + 4);
  for (int it = 0; it < 16; it++) {
    float4 e4n, x0n, x1n;
    if (it < 15) {
      const int tn = tkb + it + 1;
      e4n = *(const float4*)(emb + (size_t)tn * EDIM_ + lane * 4);
      x0n = *(const float4*)(x + (size_t)tn * DIN + lane * 8);
      x1n = *(const float4*)(x + (size_t)tn * DIN + lane * 8 + 4);
    }
    const int sl = wave * 16 + it;
    const int tk = tkb + it;
    const float ev[4] = {e4.x, e4.y, e4.z, e4.w};
    const float xv[8] = {x0.x, x0.y, x0.z, x0.w, x1.x, x1.y, x1.z, x1.w};
    double a0 = 0, a1 = 0, a2 = 0, a3 = 0;
#pragma unroll
    for (int i = 0; i < 4; ++i) {
      a0 += (double)ev[i] * rwe[i].x; a1 += (double)ev[i] * rwe[i].y;
      a2 += (double)ev[i] * rwe[i].z; a3 += (double)ev[i] * rwe[i].w;
    }
#pragma unroll
    for (int i = 0; i < 8; ++i) {
      a0 += (double)xv[i] * rwx[i].x; a1 += (double)xv[i] * rwx[i].y;
      a2 += (double)xv[i] * rwx[i].z; a3 += (double)xv[i] * rwx[i].w;
    }
    for (int off = 32; off > 0; off >>= 1) {
      a0 += __shfl_down(a0, off); a1 += __shfl_down(a1, off);
      a2 += __shfl_down(a2, off); a3 += __shfl_down(a3, off);
    }
    if (lane == 0) {
      double l[4] = {a0, a1, a2, a3};
      int bi = 0; double mx = l[0];
      for (int k = 1; k < 4; k++) if (l[k] > mx) { mx = l[k]; bi = k; }
      double p[4], s = 0;
      for (int k = 0; k < 4; k++) { p[k] = exp(l[k] - mx); s += p[k]; }
      double inv = 1.0 / s, sq = 0, sp = 0;
      for (int k = 0; k < 4; k++) { p[k] *= inv; sq += p[k] * p[k]; sp += p[k]; }
      gval[tk] = (float)p[bi];
      sgid[sl] = bi;
      double* vv = vals[sl];
      vv[0] = p[0]; vv[1] = p[1]; vv[2] = p[2]; vv[3] = p[3];
      vv[4] = sp / (sqrt(sq) + 1e-10);
    }
    e4 = e4n; x0 = x0n; x1 = x1n;
  }
  __syncthreads();
  if (t < 5) {
    double acc = 0;
    for (int k = 0; k < 64; k++) acc += vals[k][t];
    partials[(size_t)blockIdx.x * 5 + t] = acc;
  }
  if (t < 64) {
    const int e = sgid[t];
    const int tk = blockIdx.x * 64 + t;
    for (int ei = 0; ei < NEXP; ei++) {
      unsigned long long mask = __ballot(e == ei);
      if (mask == 0ull) continue;
      const int leader = __ffsll((unsigned long long)mask) - 1;
      unsigned base = 0;
      if (lane == leader) base = atomicAdd(&counts[ei], (unsigned)__popcll(mask));
      base = __shfl(base, leader, 64);
      if (e == ei) {
        const int rank = __popcll(mask & ((1ull << lane) - 1ull));
        perm[(size_t)ei * NTOK + base + rank] = (unsigned)tk;
      }
    }
  }
}

// ---------------- fused grouped expert FFN: BM=128, max B-reuse ----------------
// LDS: Xs 128KB (units (rf4*32+k16) x 1KB) @0 ; Hs 32KB (units (kloc*4+rf4)) @131072
// total exactly 160 KiB -> 1 block/CU, 8 waves
#define LDS_HS 131072
#define LDS_TOTAL 163840

__device__ __forceinline__ unsigned xorX(int k16) {
  return (unsigned)((k16 & 7) ^ ((k16 >> 3) & 3));
}

__global__ __launch_bounds__(512, 1) __attribute__((amdgpu_waves_per_eu(2, 2)))
void ffn_kernel(
    const float* __restrict__ x,
    const float* __restrict__ b1, const float* __restrict__ b2,
    const char* __restrict__ pw1, const char* __restrict__ pw2,
    const unsigned* __restrict__ counts, const unsigned* __restrict__ perm,
    const float* __restrict__ gval, const double* __restrict__ partials,
    float* __restrict__ out) {
  extern __shared__ char smem[];
  char* Xs = smem;
  char* Hs = smem + LDS_HS;

  const int tid = threadIdx.x;
  const int lane = tid & 63, wid = tid >> 6;     // 8 waves
  const int l31 = lane & 31, lh = lane >> 5;
  const int rh = wid >> 2, cs = wid & 3;         // G1 row-half / col-slice

  const unsigned c0 = counts[0], c1 = counts[1], c2 = counts[2], c3 = counts[3];
  const unsigned n0 = (c0 + 127u) >> 7, n1 = (c1 + 127u) >> 7,
                 n2 = (c2 + 127u) >> 7, n3 = (c3 + 127u) >> 7;
  const unsigned p1 = n0, p2 = n0 + n1, p3 = p2 + n2, total = p3 + n3;

  // bijective XCD swizzle for nwg=264 = 8*33
  const unsigned orig = blockIdx.x;
  const unsigned wg = (orig & 7u) * 33u + (orig >> 3);

  if (orig == 0u && wid == 0) {  // loss finalize
    double s0 = 0, s1 = 0, s2 = 0, s3 = 0, s4 = 0;
    for (int k = lane; k < 512; k += 64) {
      const double* p = partials + (size_t)k * 5;
      s0 += p[0]; s1 += p[1]; s2 += p[2]; s3 += p[3]; s4 += p[4];
    }
    for (int off = 32; off > 0; off >>= 1) {
      s0 += __shfl_down(s0, off); s1 += __shfl_down(s1, off);
      s2 += __shfl_down(s2, off); s3 += __shfl_down(s3, off);
      s4 += __shfl_down(s4, off);
    }
    if (lane == 0) {
      double mean = (s0 + s1 + s2 + s3) * 0.25;
      double var = ((s0 - mean) * (s0 - mean) + (s1 - mean) * (s1 - mean) +
                    (s2 - mean) * (s2 - mean) + (s3 - mean) * (s3 - mean)) * 0.25;
      out[16777216] = (float)(s4 / (double)NTOK);
      out[16777217] = (float)(var / (mean * mean + 1e-10));
    }
  }

  if (wg >= total) return;
  {
    const unsigned ti = wg;
    int e; unsigned pe, cnt;
    if (ti >= p3)      { e = 3; pe = p3; cnt = c3; }
    else if (ti >= p2) { e = 2; pe = p2; cnt = c2; }
    else if (ti >= p1) { e = 1; pe = p1; cnt = c1; }
    else               { e = 0; pe = 0;  cnt = c0; }
    const unsigned rows0 = (ti - pe) * 128u;
    const int mcnt = (int)min(128u, cnt - rows0);
    const size_t pbase = (size_t)e * NTOK + rows0;

    // per-lane tokens for rows lane and 64+lane
    const unsigned tokr0 = perm[pbase + (unsigned)(lane < mcnt ? lane : (mcnt - 1))];
    const unsigned tokr1 = perm[pbase + (unsigned)(64 + lane < mcnt ? 64 + lane : (mcnt - 1))];
    const float gvr0 = gval[tokr0];
    const float gvr1 = gval[tokr1];

    // stage Xs: thread -> row tid>>2 (0..127), q = tid&3; 16 chunks of 8 f32
    {
      const int r = tid >> 2, q = tid & 3;
      const unsigned tokS = perm[pbase + (unsigned)(r < mcnt ? r : mcnt - 1)];
      const float* src = x + (size_t)tokS * DIN;
      const int rf4 = r >> 5, r31 = r & 31;
#pragma unroll
      for (int i = 0; i < 16; ++i) {
        const int c = i * 4 + q;
        const float4 f0 = *(const float4*)(src + c * 8);
        const float4 f1 = *(const float4*)(src + c * 8 + 4);
        const int k16 = c >> 1, kh = c & 1;
        const unsigned slot = ((unsigned)kh << 5) | ((unsigned)r31 ^ xorX(k16));
        *(short8*)(Xs + (((rf4 * 32 + k16) << 10) + (slot << 4))) = pack8(f0, f1);
      }
    }
    asm volatile("s_waitcnt lgkmcnt(0)" ::: "memory");
    __builtin_amdgcn_s_barrier();

    // acc2: 4 rf4 x 2 cf = 128 regs
    f32x16 acc2_00 = f32x16{}, acc2_01 = f32x16{};
    f32x16 acc2_10 = f32x16{}, acc2_11 = f32x16{};
    f32x16 acc2_20 = f32x16{}, acc2_21 = f32x16{};
    f32x16 acc2_30 = f32x16{}, acc2_31 = f32x16{};

    for (int c = 0; c < 8; ++c) {   // H-chunks of 128
      // ---- GEMM1: wave = 64r (row-half rh) x 32c (slice cs), k = 512 ----
      f32x16 acc1_0 = f32x16{}, acc1_1 = f32x16{};
      const char* pB1 = pw1 + (((size_t)((e * 32 + c * 4 + cs) * 32)) << 10) + ((size_t)lane << 4);
      short8 q0 = *(const short8*)(pB1);
      short8 q1 = *(const short8*)(pB1 + 1024);
      short8 q2 = *(const short8*)(pB1 + 2048);
      short8 q3 = *(const short8*)(pB1 + 3072);
#pragma unroll
      for (int kk = 0; kk < 32; ++kk) {
        short8 b;
        if ((kk & 3) == 0) b = q0; else if ((kk & 3) == 1) b = q1;
        else if ((kk & 3) == 2) b = q2; else b = q3;
        if (kk < 28) {
          const short8 nv = *(const short8*)(pB1 + ((size_t)(kk + 4) << 10));
          if ((kk & 3) == 0) q0 = nv; else if ((kk & 3) == 1) q1 = nv;
          else if ((kk & 3) == 2) q2 = nv; else q3 = nv;
        }
        const unsigned sl = ((unsigned)lh << 5) | ((unsigned)l31 ^ xorX(kk));
        const short8 a0 = *(const short8*)(Xs + ((((rh * 2 + 0) * 32 + kk) << 10) + (sl << 4)));
        const short8 a1 = *(const short8*)(Xs + ((((rh * 2 + 1) * 32 + kk) << 10) + (sl << 4)));
        __builtin_amdgcn_s_setprio(1);
        acc1_0 = mfma32(a0, b, acc1_0);
        acc1_1 = mfma32(a1, b, acc1_1);
        __builtin_amdgcn_s_setprio(0);
      }

      const float bias = b1[e * HID + c * 128 + cs * 32 + l31];

      // preload G2 kloc 0 frags (2 streams) for chunk c
      const char* p2_0 = pw2 + ((((size_t)(e * 16 + wid * 2 + 0) * 64) + c * 8) << 10) + ((size_t)lane << 4);
      const char* p2_1 = pw2 + ((((size_t)(e * 16 + wid * 2 + 1) * 64) + c * 8) << 10) + ((size_t)lane << 4);
      short8 cb0 = *(const short8*)(p2_0);
      short8 cb1 = *(const short8*)(p2_1);

      __builtin_amdgcn_s_barrier();   // all waves done reading Hs (prev chunk)

      // ---- bias + relu -> Hs (chunk 128, unit = kloc*4 + rf4) ----
      {
        const int cloc = cs * 32 + l31;           // 0..127
        const int kloc = cloc >> 4, kh = (cloc >> 3) & 1;
        const unsigned cbyte = (unsigned)((cloc & 7) << 1);
#pragma unroll
        for (int rf = 0; rf < 2; ++rf) {
          const f32x16 av = rf ? acc1_1 : acc1_0;
          const int rf4 = rh * 2 + rf;
#pragma unroll
          for (int v = 0; v < 16; ++v) {
            const int R31 = (v & 3) + 8 * (v >> 2) + 4 * lh;
            float val = av[v] + bias;
            val = val > 0.f ? val : 0.f;
            const unsigned slot = ((unsigned)kh << 5) | ((unsigned)R31 ^ xorX(kloc));
            *(unsigned short*)(Hs + (((kloc << 2) + rf4) << 10) + (slot << 4) + cbyte) = f2bf(val);
          }
        }
      }
      asm volatile("s_waitcnt lgkmcnt(0)" ::: "memory");
      __builtin_amdgcn_s_barrier();

      // ---- GEMM2: wave = 128r x 64d (2 streams), k-chunk 128, 8 MFMA/iter ----
#pragma unroll
      for (int kloc = 0; kloc < 8; ++kloc) {
        short8 n0, n1;
        if (kloc < 7) {
          n0 = *(const short8*)(p2_0 + ((size_t)(kloc + 1) << 10));
          n1 = *(const short8*)(p2_1 + ((size_t)(kloc + 1) << 10));
        }
        const unsigned sl = ((unsigned)lh << 5) | ((unsigned)l31 ^ xorX(kloc));
        const short8 h0 = *(const short8*)(Hs + ((((kloc << 2) + 0) << 10) + (sl << 4)));
        const short8 h1 = *(const short8*)(Hs + ((((kloc << 2) + 1) << 10) + (sl << 4)));
        const short8 h2 = *(const short8*)(Hs + ((((kloc << 2) + 2) << 10) + (sl << 4)));
        const short8 h3 = *(const short8*)(Hs + ((((kloc << 2) + 3) << 10) + (sl << 4)));
        __builtin_amdgcn_s_setprio(1);
        acc2_00 = mfma32(h0, cb0, acc2_00);  acc2_01 = mfma32(h0, cb1, acc2_01);
        acc2_10 = mfma32(h1, cb0, acc2_10);  acc2_11 = mfma32(h1, cb1, acc2_11);
        acc2_20 = mfma32(h2, cb0, acc2_20);  acc2_21 = mfma32(h2, cb1, acc2_21);
        acc2_30 = mfma32(h3, cb0, acc2_30);  acc2_31 = mfma32(h3, cb1, acc2_31);
        __builtin_amdgcn_s_setprio(0);
        if (kloc < 7) { cb0 = n0; cb1 = n1; }
      }
    }

    // ---- epilogue: (y + b2) * gate -> out ----
    const int dbase = wid * 64 + l31;
    const float bv0 = b2[e * DIN + dbase];
    const float bv1 = b2[e * DIN + dbase + 32];
#pragma unroll
    for (int rf4 = 0; rf4 < 4; ++rf4) {
      const f32x16 y0 = (rf4 == 0) ? acc2_00 : (rf4 == 1) ? acc2_10 : (rf4 == 2) ? acc2_20 : acc2_30;
      const f32x16 y1 = (rf4 == 0) ? acc2_01 : (rf4 == 1) ? acc2_11 : (rf4 == 2) ? acc2_21 : acc2_31;
#pragma unroll
      for (int v = 0; v < 16; ++v) {
        const int R31 = (v & 3) + 8 * (v >> 2) + 4 * lh;
        const int R = rf4 * 32 + R31;
        const int lsel = (rf4 & 1) * 32 + R31;
        const unsigned tk = (rf4 < 2) ? (unsigned)__shfl((int)tokr0, lsel)
                                      : (unsigned)__shfl((int)tokr1, lsel);
        const float gv = (rf4 < 2) ? __shfl(gvr0, lsel) : __shfl(gvr1, lsel);
        if (R < mcnt) {
          float* orow = out + (size_t)tk * DIN + dbase;
          orow[0]  = (y0[v] + bv0) * gv;
          orow[32] = (y1[v] + bv1) * gv;
        }
      }
    }
  }
}

extern "C" void kernel_launch(void* const* d_in, const int* in_sizes, int n_in,
                              void* d_out, int out_size, void* d_ws, size_t ws_size,
                              hipStream_t stream) {
  const float* x   = (const float*)d_in[0];
  const float* emb = (const float*)d_in[1];
  const float* rw  = (const float*)d_in[2];
  const float* w1  = (const float*)d_in[3];
  const float* b1  = (const float*)d_in[4];
  const float* w2  = (const float*)d_in[5];
  const float* b2  = (const float*)d_in[6];
  float* out = (float*)d_out;

  char* ws = (char*)d_ws;
  unsigned* counts = (unsigned*)(ws + OFF_COUNTS);
  float* gval = (float*)(ws + OFF_GVAL);
  unsigned* perm = (unsigned*)(ws + OFF_PERM);
  double* partials = (double*)(ws + OFF_PART);
  char* pw1 = ws + OFF_WB1;
  char* pw2 = ws + OFF_WB2;

  hipMemsetAsync(ws, 0, 256, stream);
  router_kernel<<<512, 256, 0, stream>>>(x, emb, rw, gval, counts, perm, partials,
                                         w1, w2, pw1, pw2);

  hipFuncSetAttribute((const void*)ffn_kernel, hipFuncAttributeMaxDynamicSharedMemorySize, LDS_TOTAL);
  ffn_kernel<<<264, 512, LDS_TOTAL, stream>>>(x, b1, b2, pw1, pw2, counts, perm, gval, partials, out);
}

// Round 19
// 179.645 us; speedup vs baseline: 1.0635x; 1.0635x over previous
//
#include <hip/hip_runtime.h>
#include <hip/hip_bf16.h>
#include <cstdint>
#include <cstddef>

#define NTOK 32768
#define DIN 512
#define EDIM_ 256
#define HID 1024
#define NEXP 4

typedef __attribute__((ext_vector_type(8))) short short8;
typedef __attribute__((ext_vector_type(16))) float f32x16;

// ---- workspace layout (bytes) ----
#define OFF_COUNTS 0
#define OFF_GVAL   256
#define OFF_PERM   (OFF_GVAL + 131072)
#define OFF_PART   (OFF_PERM + 524288)
#define OFF_WB1    (OFF_PART + 40960)
#define OFF_WB2    (OFF_WB1 + 4194304)

__device__ __forceinline__ unsigned short f2bf(float f) {
  unsigned u = __float_as_uint(f);
  u = (u + 0x7fffu + ((u >> 16) & 1u)) >> 16;
  return (unsigned short)u;
}

__device__ __forceinline__ f32x16 mfma32(short8 a, short8 b, f32x16 c) {
  return __builtin_amdgcn_mfma_f32_32x32x16_bf16(a, b, c, 0, 0, 0);
}

__device__ __forceinline__ short8 pack8(float4 f0, float4 f1) {
  short8 v;
  v[0] = (short)f2bf(f0.x); v[1] = (short)f2bf(f0.y);
  v[2] = (short)f2bf(f0.z); v[3] = (short)f2bf(f0.w);
  v[4] = (short)f2bf(f1.x); v[5] = (short)f2bf(f1.y);
  v[6] = (short)f2bf(f1.z); v[7] = (short)f2bf(f1.w);
  return v;
}

// ---------------- router + W pack: 1024 blocks x 32 tokens (halved serial chain) ----------------
__global__ __launch_bounds__(256) void router_kernel(const float* __restrict__ x,
                                                     const float* __restrict__ emb,
                                                     const float* __restrict__ rw,
                                                     float* __restrict__ gval,
                                                     unsigned* __restrict__ counts,
                                                     unsigned* __restrict__ perm,
                                                     double* __restrict__ partials,
                                                     const float* __restrict__ w1,
                                                     const float* __restrict__ w2,
                                                     char* __restrict__ pw1,
                                                     char* __restrict__ pw2) {
  __shared__ float lbuf[32][132];
  __shared__ double vals[32][5];
  __shared__ int sgid[32];
  const int t = threadIdx.x;
  const int wave = t >> 6, lane = t & 63;
  const int l31 = lane & 31, lh = lane >> 5;

  float4 rwe[4], rwx[8];
#pragma unroll
  for (int i = 0; i < 4; ++i) rwe[i] = *(const float4*)(rw + (lane * 4 + i) * 4);
#pragma unroll
  for (int i = 0; i < 8; ++i) rwx[i] = *(const float4*)(rw + (256 + lane * 8 + i) * 4);

  // ---- pack: each block does ONE region of ONE matrix ----
  {
    const unsigned r = blockIdx.x;
    const int m = (r >= 512u) ? 1 : 0;
    const unsigned rr = r & 511u;
    const unsigned e = rr >> 7;
    unsigned nb, k8, stride;
    const float* srcb;
    if (m == 0) { nb = (rr >> 2) & 31u; k8 = rr & 3u; stride = 512;
      srcb = w1 + ((size_t)e << 19) + (size_t)nb * 32 * 512 + k8 * 128; }
    else        { nb = (rr >> 3) & 15u; k8 = rr & 7u; stride = 1024;
      srcb = w2 + ((size_t)e << 19) + (size_t)nb * 32 * 1024 + k8 * 128; }
    {
      const int row = t >> 3, coff = (t & 7) * 16;
      const float* s = srcb + (size_t)row * stride + coff;
      float4 f0 = *(const float4*)(s), f1 = *(const float4*)(s + 4);
      float4 f2 = *(const float4*)(s + 8), f3 = *(const float4*)(s + 12);
      *(float4*)&lbuf[row][coff] = f0;  *(float4*)&lbuf[row][coff + 4] = f1;
      *(float4*)&lbuf[row][coff + 8] = f2; *(float4*)&lbuf[row][coff + 12] = f3;
    }
    __syncthreads();
#pragma unroll
    for (int pass = 0; pass < 2; ++pass) {
      const int u = pass * 4 + (t >> 6);
      float4 f0 = *(const float4*)&lbuf[l31][u * 16 + lh * 8];
      float4 f1 = *(const float4*)&lbuf[l31][u * 16 + lh * 8 + 4];
      short8 v = pack8(f0, f1);
      size_t unit;
      char* dst;
      if (m == 0) { unit = ((size_t)(e * 32 + nb) * 32) + k8 * 8 + u; dst = pw1; }
      else        { unit = ((size_t)(e * 16 + nb) * 64) + k8 * 8 + u; dst = pw2; }
      *(short8*)(dst + (unit << 10) + lane * 16) = v;
    }
  }

  // ---- router: 8 serial rounds per wave (32 tokens/block) + depth-1 prefetch ----
  const int tkb = blockIdx.x * 32 + wave * 8;
  float4 e4 = *(const float4*)(emb + (size_t)tkb * EDIM_ + lane * 4);
  float4 x0 = *(const float4*)(x + (size_t)tkb * DIN + lane * 8);
  float4 x1 = *(const float4*)(x + (size_t)tkb * DIN + lane * 8 + 4);
  for (int it = 0; it < 8; it++) {
    float4 e4n, x0n, x1n;
    if (it < 7) {
      const int tn = tkb + it + 1;
      e4n = *(const float4*)(emb + (size_t)tn * EDIM_ + lane * 4);
      x0n = *(const float4*)(x + (size_t)tn * DIN + lane * 8);
      x1n = *(const float4*)(x + (size_t)tn * DIN + lane * 8 + 4);
    }
    const int sl = wave * 8 + it;
    const int tk = tkb + it;
    const float ev[4] = {e4.x, e4.y, e4.z, e4.w};
    const float xv[8] = {x0.x, x0.y, x0.z, x0.w, x1.x, x1.y, x1.z, x1.w};
    double a0 = 0, a1 = 0, a2 = 0, a3 = 0;
#pragma unroll
    for (int i = 0; i < 4; ++i) {
      a0 += (double)ev[i] * rwe[i].x; a1 += (double)ev[i] * rwe[i].y;
      a2 += (double)ev[i] * rwe[i].z; a3 += (double)ev[i] * rwe[i].w;
    }
#pragma unroll
    for (int i = 0; i < 8; ++i) {
      a0 += (double)xv[i] * rwx[i].x; a1 += (double)xv[i] * rwx[i].y;
      a2 += (double)xv[i] * rwx[i].z; a3 += (double)xv[i] * rwx[i].w;
    }
    for (int off = 32; off > 0; off >>= 1) {
      a0 += __shfl_down(a0, off); a1 += __shfl_down(a1, off);
      a2 += __shfl_down(a2, off); a3 += __shfl_down(a3, off);
    }
    if (lane == 0) {
      double l[4] = {a0, a1, a2, a3};
      int bi = 0; double mx = l[0];
      for (int k = 1; k < 4; k++) if (l[k] > mx) { mx = l[k]; bi = k; }
      double p[4], s = 0;
      for (int k = 0; k < 4; k++) { p[k] = exp(l[k] - mx); s += p[k]; }
      double inv = 1.0 / s, sq = 0, sp = 0;
      for (int k = 0; k < 4; k++) { p[k] *= inv; sq += p[k] * p[k]; sp += p[k]; }
      gval[tk] = (float)p[bi];
      sgid[sl] = bi;
      double* vv = vals[sl];
      vv[0] = p[0]; vv[1] = p[1]; vv[2] = p[2]; vv[3] = p[3];
      vv[4] = sp / (sqrt(sq) + 1e-10);
    }
    e4 = e4n; x0 = x0n; x1 = x1n;
  }
  __syncthreads();
  if (t < 5) {
    double acc = 0;
    for (int k = 0; k < 32; k++) acc += vals[k][t];
    partials[(size_t)blockIdx.x * 5 + t] = acc;
  }
  if (t < 64) {  // wave 0: scatter 32 tokens (lanes 32..63 inactive in mask)
    const int e = (t < 32) ? sgid[t] : -1;
    const int tk = blockIdx.x * 32 + t;
    for (int ei = 0; ei < NEXP; ei++) {
      unsigned long long mask = __ballot(e == ei);
      if (mask == 0ull) continue;
      const int leader = __ffsll((unsigned long long)mask) - 1;
      unsigned base = 0;
      if (lane == leader) base = atomicAdd(&counts[ei], (unsigned)__popcll(mask));
      base = __shfl(base, leader, 64);
      if (e == ei) {
        const int rank = __popcll(mask & ((1ull << lane) - 1ull));
        perm[(size_t)ei * NTOK + base + rank] = (unsigned)tk;
      }
    }
  }
}

// ---------------- fused grouped expert FFN: R17 (validated best, byte-identical) ----------------
// LDS: Xs 64KB @0 ; Hs 16KB (chunk 128) @65536 ; total 81920
#define LDS_HS 65536
#define LDS_TOTAL 81920

__device__ __forceinline__ unsigned xorX(int k16) {
  return (unsigned)((k16 & 7) ^ ((k16 >> 3) & 3));
}

__global__ __launch_bounds__(256, 2) __attribute__((amdgpu_waves_per_eu(2, 2)))
void ffn_kernel(
    const float* __restrict__ x,
    const float* __restrict__ b1, const float* __restrict__ b2,
    const char* __restrict__ pw1, const char* __restrict__ pw2,
    const unsigned* __restrict__ counts, const unsigned* __restrict__ perm,
    const float* __restrict__ gval, const double* __restrict__ partials,
    float* __restrict__ out) {
  extern __shared__ char smem[];
  char* Xs = smem;
  char* Hs = smem + LDS_HS;

  const int tid = threadIdx.x;
  const int lane = tid & 63, wid = tid >> 6;     // 4 waves
  const int l31 = lane & 31, lh = lane >> 5;

  const unsigned c0 = counts[0], c1 = counts[1], c2 = counts[2], c3 = counts[3];
  const unsigned n0 = (c0 + 63u) >> 6, n1 = (c1 + 63u) >> 6, n2 = (c2 + 63u) >> 6, n3 = (c3 + 63u) >> 6;
  const unsigned p1 = n0, p2 = n0 + n1, p3 = p2 + n2, total = p3 + n3;

  // bijective XCD swizzle for nwg=516: q=64, r=4
  const unsigned orig = blockIdx.x;
  const unsigned xcd = orig & 7u, jj0 = orig >> 3;
  const unsigned wg = (xcd < 4u ? xcd * 65u : 260u + (xcd - 4u) * 64u) + jj0;

  if (orig == 0u && wid == 0) {  // loss finalize (partials now 1024 x 5)
    double s0 = 0, s1 = 0, s2 = 0, s3 = 0, s4 = 0;
    for (int k = lane; k < 1024; k += 64) {
      const double* p = partials + (size_t)k * 5;
      s0 += p[0]; s1 += p[1]; s2 += p[2]; s3 += p[3]; s4 += p[4];
    }
    for (int off = 32; off > 0; off >>= 1) {
      s0 += __shfl_down(s0, off); s1 += __shfl_down(s1, off);
      s2 += __shfl_down(s2, off); s3 += __shfl_down(s3, off);
      s4 += __shfl_down(s4, off);
    }
    if (lane == 0) {
      double mean = (s0 + s1 + s2 + s3) * 0.25;
      double var = ((s0 - mean) * (s0 - mean) + (s1 - mean) * (s1 - mean) +
                    (s2 - mean) * (s2 - mean) + (s3 - mean) * (s3 - mean)) * 0.25;
      out[16777216] = (float)(s4 / (double)NTOK);
      out[16777217] = (float)(var / (mean * mean + 1e-10));
    }
  }

  if (wg >= total) return;
  {
    const unsigned ti = wg;
    int e; unsigned pe, cnt;
    if (ti >= p3)      { e = 3; pe = p3; cnt = c3; }
    else if (ti >= p2) { e = 2; pe = p2; cnt = c2; }
    else if (ti >= p1) { e = 1; pe = p1; cnt = c1; }
    else               { e = 0; pe = 0;  cnt = c0; }
    const unsigned rows0 = (ti - pe) * 64u;
    const int mcnt = (int)min(64u, cnt - rows0);
    const size_t pbase = (size_t)e * NTOK + rows0;

    const unsigned tokr = perm[pbase + (unsigned)(lane < mcnt ? lane : (mcnt - 1))];
    const float gvr = gval[tokr];

    // stage Xs: thread -> row tid>>2, col-chunks c = i*4 + (tid&3), 8 f32 each
    {
      const int r = tid >> 2, q = tid & 3;
      const unsigned tokS = perm[pbase + (unsigned)(r < mcnt ? r : mcnt - 1)];
      const float* src = x + (size_t)tokS * DIN;
      const int rf = r >> 5, r31 = r & 31;
#pragma unroll
      for (int i = 0; i < 16; ++i) {
        const int c = i * 4 + q;
        const float4 f0 = *(const float4*)(src + c * 8);
        const float4 f1 = *(const float4*)(src + c * 8 + 4);
        const int k16 = c >> 1, kh = c & 1;
        const unsigned slot = ((unsigned)kh << 5) | ((unsigned)r31 ^ xorX(k16));
        *(short8*)(Xs + (((rf * 32 + k16) << 10) + (slot << 4))) = pack8(f0, f1);
      }
    }
    asm volatile("s_waitcnt lgkmcnt(0)" ::: "memory");
    __builtin_amdgcn_s_barrier();

    // acc2: 2 rf x 4 cf = 128 regs
    f32x16 acc2_00 = f32x16{}, acc2_01 = f32x16{}, acc2_02 = f32x16{}, acc2_03 = f32x16{};
    f32x16 acc2_10 = f32x16{}, acc2_11 = f32x16{}, acc2_12 = f32x16{}, acc2_13 = f32x16{};

    for (int c = 0; c < 8; ++c) {   // H-chunks of 128
      // ---- GEMM1: wave = 64r x 32c, k = 512, depth-4 B queue + 1-ahead A prefetch ----
      f32x16 acc1_0 = f32x16{}, acc1_1 = f32x16{};
      const char* pB1 = pw1 + (((size_t)((e * 32 + c * 4 + wid) * 32)) << 10) + ((size_t)lane << 4);
      short8 q0 = *(const short8*)(pB1);
      short8 q1 = *(const short8*)(pB1 + 1024);
      short8 q2 = *(const short8*)(pB1 + 2048);
      short8 q3 = *(const short8*)(pB1 + 3072);
      unsigned slc = ((unsigned)lh << 5) | ((unsigned)l31 ^ xorX(0));
      short8 a0c = *(const short8*)(Xs + (slc << 4));
      short8 a1c = *(const short8*)(Xs + ((32 << 10) + (slc << 4)));
#pragma unroll
      for (int kk = 0; kk < 32; ++kk) {
        short8 a0n, a1n;
        if (kk < 31) {
          const unsigned sn = ((unsigned)lh << 5) | ((unsigned)l31 ^ xorX(kk + 1));
          a0n = *(const short8*)(Xs + (((kk + 1) << 10) + (sn << 4)));
          a1n = *(const short8*)(Xs + (((33 + kk) << 10) + (sn << 4)));
        }
        short8 b;
        if ((kk & 3) == 0) b = q0; else if ((kk & 3) == 1) b = q1;
        else if ((kk & 3) == 2) b = q2; else b = q3;
        if (kk < 28) {
          const short8 nv = *(const short8*)(pB1 + ((size_t)(kk + 4) << 10));
          if ((kk & 3) == 0) q0 = nv; else if ((kk & 3) == 1) q1 = nv;
          else if ((kk & 3) == 2) q2 = nv; else q3 = nv;
        }
        __builtin_amdgcn_s_setprio(1);
        acc1_0 = mfma32(a0c, b, acc1_0);
        acc1_1 = mfma32(a1c, b, acc1_1);
        __builtin_amdgcn_s_setprio(0);
        a0c = a0n; a1c = a1n;
      }

      const float bias = b1[e * HID + c * 128 + wid * 32 + l31];

      // preload G2 kloc 0 frags for chunk c (4 streams; hidden under barrier)
      const char* p2_0 = pw2 + ((((size_t)(e * 16 + wid * 4) * 64) + c * 8) << 10) + ((size_t)lane << 4);
      const char* p2_1 = p2_0 + ((size_t)64 << 10);
      const char* p2_2 = p2_0 + ((size_t)128 << 10);
      const char* p2_3 = p2_0 + ((size_t)192 << 10);
      short8 cb0 = *(const short8*)(p2_0);
      short8 cb1 = *(const short8*)(p2_1);
      short8 cb2 = *(const short8*)(p2_2);
      short8 cb3 = *(const short8*)(p2_3);

      __builtin_amdgcn_s_barrier();   // all waves done reading Hs (prev chunk)

      // ---- bias + relu -> Hs (chunk 128, frag layout: unit = kloc*2+rf) ----
      {
        const int cloc = wid * 32 + l31;          // 0..127
        const int kloc = cloc >> 4, kh = (cloc >> 3) & 1;
        const unsigned cbyte = (unsigned)((cloc & 7) << 1);
#pragma unroll
        for (int rf = 0; rf < 2; ++rf) {
          const f32x16 av = rf ? acc1_1 : acc1_0;
#pragma unroll
          for (int v = 0; v < 16; ++v) {
            const int R31 = (v & 3) + 8 * (v >> 2) + 4 * lh;
            float val = av[v] + bias;
            val = val > 0.f ? val : 0.f;
            const unsigned slot = ((unsigned)kh << 5) | ((unsigned)R31 ^ xorX(kloc));
            *(unsigned short*)(Hs + (((kloc << 1) + rf) << 10) + (slot << 4) + cbyte) = f2bf(val);
          }
        }
      }
      asm volatile("s_waitcnt lgkmcnt(0)" ::: "memory");
      __builtin_amdgcn_s_barrier();

      // ---- GEMM2: wave = 64r x 128d (4 streams), k-chunk 128, 8 MFMA/iter + 1-ahead H prefetch ----
      unsigned sg = ((unsigned)lh << 5) | ((unsigned)l31 ^ xorX(0));
      short8 h0c = *(const short8*)(Hs + (sg << 4));
      short8 h1c = *(const short8*)(Hs + ((1 << 10) + (sg << 4)));
#pragma unroll
      for (int kloc = 0; kloc < 8; ++kloc) {
        short8 h0n, h1n, n0, n1, n2, n3;
        if (kloc < 7) {
          const unsigned sn = ((unsigned)lh << 5) | ((unsigned)l31 ^ xorX(kloc + 1));
          h0n = *(const short8*)(Hs + ((((kloc + 1) << 1) + 0) << 10) + (sn << 4));
          h1n = *(const short8*)(Hs + ((((kloc + 1) << 1) + 1) << 10) + (sn << 4));
          n0 = *(const short8*)(p2_0 + ((size_t)(kloc + 1) << 10));
          n1 = *(const short8*)(p2_1 + ((size_t)(kloc + 1) << 10));
          n2 = *(const short8*)(p2_2 + ((size_t)(kloc + 1) << 10));
          n3 = *(const short8*)(p2_3 + ((size_t)(kloc + 1) << 10));
        }
        __builtin_amdgcn_s_setprio(1);
        acc2_00 = mfma32(h0c, cb0, acc2_00);  acc2_10 = mfma32(h1c, cb0, acc2_10);
        acc2_01 = mfma32(h0c, cb1, acc2_01);  acc2_11 = mfma32(h1c, cb1, acc2_11);
        acc2_02 = mfma32(h0c, cb2, acc2_02);  acc2_12 = mfma32(h1c, cb2, acc2_12);
        acc2_03 = mfma32(h0c, cb3, acc2_03);  acc2_13 = mfma32(h1c, cb3, acc2_13);
        __builtin_amdgcn_s_setprio(0);
        if (kloc < 7) { h0c = h0n; h1c = h1n; cb0 = n0; cb1 = n1; cb2 = n2; cb3 = n3; }
      }
    }

    // ---- epilogue: (y + b2) * gate -> out ----
    const int dbase = wid * 128 + l31;
    const float bv0 = b2[e * DIN + dbase];
    const float bv1 = b2[e * DIN + dbase + 32];
    const float bv2 = b2[e * DIN + dbase + 64];
    const float bv3 = b2[e * DIN + dbase + 96];
#pragma unroll
    for (int rf = 0; rf < 2; ++rf) {
      const f32x16 y0 = rf ? acc2_10 : acc2_00;
      const f32x16 y1 = rf ? acc2_11 : acc2_01;
      const f32x16 y2 = rf ? acc2_12 : acc2_02;
      const f32x16 y3 = rf ? acc2_13 : acc2_03;
#pragma unroll
      for (int v = 0; v < 16; ++v) {
        const int R = rf * 32 + (v & 3) + 8 * (v >> 2) + 4 * lh;
        const unsigned tk = (unsigned)__shfl((int)tokr, R);
        const float gv = __shfl(gvr, R);
        if (R < mcnt) {
          float* orow = out + (size_t)tk * DIN + dbase;
          orow[0]  = (y0[v] + bv0) * gv;
          orow[32] = (y1[v] + bv1) * gv;
          orow[64] = (y2[v] + bv2) * gv;
          orow[96] = (y3[v] + bv3) * gv;
        }
      }
    }
  }
}

extern "C" void kernel_launch(void* const* d_in, const int* in_sizes, int n_in,
                              void* d_out, int out_size, void* d_ws, size_t ws_size,
                              hipStream_t stream) {
  const float* x   = (const float*)d_in[0];
  const float* emb = (const float*)d_in[1];
  const float* rw  = (const float*)d_in[2];
  const float* w1  = (const float*)d_in[3];
  const float* b1  = (const float*)d_in[4];
  const float* w2  = (const float*)d_in[5];
  const float* b2  = (const float*)d_in[6];
  float* out = (float*)d_out;

  char* ws = (char*)d_ws;
  unsigned* counts = (unsigned*)(ws + OFF_COUNTS);
  float* gval = (float*)(ws + OFF_GVAL);
  unsigned* perm = (unsigned*)(ws + OFF_PERM);
  double* partials = (double*)(ws + OFF_PART);
  char* pw1 = ws + OFF_WB1;
  char* pw2 = ws + OFF_WB2;

  hipMemsetAsync(ws, 0, 256, stream);
  router_kernel<<<1024, 256, 0, stream>>>(x, emb, rw, gval, counts, perm, partials,
                                          w1, w2, pw1, pw2);

  hipFuncSetAttribute((const void*)ffn_kernel, hipFuncAttributeMaxDynamicSharedMemorySize, LDS_TOTAL);
  ffn_kernel<<<516, 256, LDS_TOTAL, stream>>>(x, b1, b2, pw1, pw2, counts, perm, gval, partials, out);
}

// Round 20
// 164.251 us; speedup vs baseline: 1.1632x; 1.0937x over previous
//
#include <hip/hip_runtime.h>
#include <hip/hip_bf16.h>
#include <cstdint>
#include <cstddef>

#define NTOK 32768
#define DIN 512
#define EDIM_ 256
#define HID 1024
#define NEXP 4

typedef __attribute__((ext_vector_type(8))) short short8;
typedef __attribute__((ext_vector_type(16))) float f32x16;

// ---- workspace layout (bytes) ----
#define OFF_COUNTS 0
#define OFF_GVAL   256
#define OFF_PERM   (OFF_GVAL + 131072)
#define OFF_PART   (OFF_PERM + 524288)
#define OFF_WB1    (OFF_PART + 40960)
#define OFF_WB2    (OFF_WB1 + 4194304)

__device__ __forceinline__ unsigned short f2bf(float f) {
  unsigned u = __float_as_uint(f);
  u = (u + 0x7fffu + ((u >> 16) & 1u)) >> 16;
  return (unsigned short)u;
}

__device__ __forceinline__ f32x16 mfma32(short8 a, short8 b, f32x16 c) {
  return __builtin_amdgcn_mfma_f32_32x32x16_bf16(a, b, c, 0, 0, 0);
}

__device__ __forceinline__ short8 pack8(float4 f0, float4 f1) {
  short8 v;
  v[0] = (short)f2bf(f0.x); v[1] = (short)f2bf(f0.y);
  v[2] = (short)f2bf(f0.z); v[3] = (short)f2bf(f0.w);
  v[4] = (short)f2bf(f1.x); v[5] = (short)f2bf(f1.y);
  v[6] = (short)f2bf(f1.z); v[7] = (short)f2bf(f1.w);
  return v;
}

// ---------------- router + W pack (R17-validated best) ----------------
__global__ __launch_bounds__(256) void router_kernel(const float* __restrict__ x,
                                                     const float* __restrict__ emb,
                                                     const float* __restrict__ rw,
                                                     float* __restrict__ gval,
                                                     unsigned* __restrict__ counts,
                                                     unsigned* __restrict__ perm,
                                                     double* __restrict__ partials,
                                                     const float* __restrict__ w1,
                                                     const float* __restrict__ w2,
                                                     char* __restrict__ pw1,
                                                     char* __restrict__ pw2) {
  __shared__ float lbuf[32][132];
  __shared__ double vals[64][5];
  __shared__ int sgid[64];
  const int t = threadIdx.x;
  const int wave = t >> 6, lane = t & 63;
  const int l31 = lane & 31, lh = lane >> 5;

  // per-lane router weights: issue before pack so latency hides under it
  float4 rwe[4], rwx[8];
#pragma unroll
  for (int i = 0; i < 4; ++i) rwe[i] = *(const float4*)(rw + (lane * 4 + i) * 4);
#pragma unroll
  for (int i = 0; i < 8; ++i) rwx[i] = *(const float4*)(rw + (256 + lane * 8 + i) * 4);

#pragma unroll
  for (int m = 0; m < 2; ++m) {
    const unsigned r = blockIdx.x;
    const unsigned e = r >> 7;
    unsigned nb, k8, stride;
    const float* srcb;
    if (m == 0) { nb = (r >> 2) & 31u; k8 = r & 3u; stride = 512;
      srcb = w1 + ((size_t)e << 19) + (size_t)nb * 32 * 512 + k8 * 128; }
    else        { nb = (r >> 3) & 15u; k8 = r & 7u; stride = 1024;
      srcb = w2 + ((size_t)e << 19) + (size_t)nb * 32 * 1024 + k8 * 128; }
    {
      const int row = t >> 3, coff = (t & 7) * 16;
      const float* s = srcb + (size_t)row * stride + coff;
      float4 f0 = *(const float4*)(s), f1 = *(const float4*)(s + 4);
      float4 f2 = *(const float4*)(s + 8), f3 = *(const float4*)(s + 12);
      *(float4*)&lbuf[row][coff] = f0;  *(float4*)&lbuf[row][coff + 4] = f1;
      *(float4*)&lbuf[row][coff + 8] = f2; *(float4*)&lbuf[row][coff + 12] = f3;
    }
    __syncthreads();
#pragma unroll
    for (int pass = 0; pass < 2; ++pass) {
      const int u = pass * 4 + (t >> 6);
      float4 f0 = *(const float4*)&lbuf[l31][u * 16 + lh * 8];
      float4 f1 = *(const float4*)&lbuf[l31][u * 16 + lh * 8 + 4];
      short8 v = pack8(f0, f1);
      size_t unit;
      char* dst;
      if (m == 0) { unit = ((size_t)(e * 32 + nb) * 32) + k8 * 8 + u; dst = pw1; }
      else        { unit = ((size_t)(e * 16 + nb) * 64) + k8 * 8 + u; dst = pw2; }
      *(short8*)(dst + (unit << 10) + lane * 16) = v;
    }
    __syncthreads();
  }

  // ---- router: serial 16 rounds (validated numerics) + depth-1 token prefetch ----
  const int tkb = blockIdx.x * 64 + wave * 16;
  float4 e4 = *(const float4*)(emb + (size_t)tkb * EDIM_ + lane * 4);
  float4 x0 = *(const float4*)(x + (size_t)tkb * DIN + lane * 8);
  float4 x1 = *(const float4*)(x + (size_t)tkb * DIN + lane * 8 + 4);
  for (int it = 0; it < 16; it++) {
    float4 e4n, x0n, x1n;
    if (it < 15) {
      const int tn = tkb + it + 1;
      e4n = *(const float4*)(emb + (size_t)tn * EDIM_ + lane * 4);
      x0n = *(const float4*)(x + (size_t)tn * DIN + lane * 8);
      x1n = *(const float4*)(x + (size_t)tn * DIN + lane * 8 + 4);
    }
    const int sl = wave * 16 + it;
    const int tk = tkb + it;
    const float ev[4] = {e4.x, e4.y, e4.z, e4.w};
    const float xv[8] = {x0.x, x0.y, x0.z, x0.w, x1.x, x1.y, x1.z, x1.w};
    double a0 = 0, a1 = 0, a2 = 0, a3 = 0;
#pragma unroll
    for (int i = 0; i < 4; ++i) {
      a0 += (double)ev[i] * rwe[i].x; a1 += (double)ev[i] * rwe[i].y;
      a2 += (double)ev[i] * rwe[i].z; a3 += (double)ev[i] * rwe[i].w;
    }
#pragma unroll
    for (int i = 0; i < 8; ++i) {
      a0 += (double)xv[i] * rwx[i].x; a1 += (double)xv[i] * rwx[i].y;
      a2 += (double)xv[i] * rwx[i].z; a3 += (double)xv[i] * rwx[i].w;
    }
    for (int off = 32; off > 0; off >>= 1) {
      a0 += __shfl_down(a0, off); a1 += __shfl_down(a1, off);
      a2 += __shfl_down(a2, off); a3 += __shfl_down(a3, off);
    }
    if (lane == 0) {
      double l[4] = {a0, a1, a2, a3};
      int bi = 0; double mx = l[0];
      for (int k = 1; k < 4; k++) if (l[k] > mx) { mx = l[k]; bi = k; }
      double p[4], s = 0;
      for (int k = 0; k < 4; k++) { p[k] = exp(l[k] - mx); s += p[k]; }
      double inv = 1.0 / s, sq = 0, sp = 0;
      for (int k = 0; k < 4; k++) { p[k] *= inv; sq += p[k] * p[k]; sp += p[k]; }
      gval[tk] = (float)p[bi];
      sgid[sl] = bi;
      double* vv = vals[sl];
      vv[0] = p[0]; vv[1] = p[1]; vv[2] = p[2]; vv[3] = p[3];
      vv[4] = sp / (sqrt(sq) + 1e-10);
    }
    e4 = e4n; x0 = x0n; x1 = x1n;
  }
  __syncthreads();
  if (t < 5) {
    double acc = 0;
    for (int k = 0; k < 64; k++) acc += vals[k][t];
    partials[(size_t)blockIdx.x * 5 + t] = acc;
  }
  if (t < 64) {
    const int e = sgid[t];
    const int tk = blockIdx.x * 64 + t;
    for (int ei = 0; ei < NEXP; ei++) {
      unsigned long long mask = __ballot(e == ei);
      if (mask == 0ull) continue;
      const int leader = __ffsll((unsigned long long)mask) - 1;
      unsigned base = 0;
      if (lane == leader) base = atomicAdd(&counts[ei], (unsigned)__popcll(mask));
      base = __shfl(base, leader, 64);
      if (e == ei) {
        const int rank = __popcll(mask & ((1ull << lane) - 1ull));
        perm[(size_t)ei * NTOK + base + rank] = (unsigned)tk;
      }
    }
  }
}

// ---------------- fused grouped expert FFN: R17 (validated best) ----------------
// LDS: Xs 64KB @0 ; Hs 16KB (chunk 128) @65536 ; total 81920
#define LDS_HS 65536
#define LDS_TOTAL 81920

__device__ __forceinline__ unsigned xorX(int k16) {
  return (unsigned)((k16 & 7) ^ ((k16 >> 3) & 3));
}

__global__ __launch_bounds__(256, 2) __attribute__((amdgpu_waves_per_eu(2, 2)))
void ffn_kernel(
    const float* __restrict__ x,
    const float* __restrict__ b1, const float* __restrict__ b2,
    const char* __restrict__ pw1, const char* __restrict__ pw2,
    const unsigned* __restrict__ counts, const unsigned* __restrict__ perm,
    const float* __restrict__ gval, const double* __restrict__ partials,
    float* __restrict__ out) {
  extern __shared__ char smem[];
  char* Xs = smem;
  char* Hs = smem + LDS_HS;

  const int tid = threadIdx.x;
  const int lane = tid & 63, wid = tid >> 6;     // 4 waves
  const int l31 = lane & 31, lh = lane >> 5;

  const unsigned c0 = counts[0], c1 = counts[1], c2 = counts[2], c3 = counts[3];
  const unsigned n0 = (c0 + 63u) >> 6, n1 = (c1 + 63u) >> 6, n2 = (c2 + 63u) >> 6, n3 = (c3 + 63u) >> 6;
  const unsigned p1 = n0, p2 = n0 + n1, p3 = p2 + n2, total = p3 + n3;

  // bijective XCD swizzle for nwg=516: q=64, r=4
  const unsigned orig = blockIdx.x;
  const unsigned xcd = orig & 7u, jj0 = orig >> 3;
  const unsigned wg = (xcd < 4u ? xcd * 65u : 260u + (xcd - 4u) * 64u) + jj0;

  if (orig == 0u && wid == 0) {  // loss finalize
    double s0 = 0, s1 = 0, s2 = 0, s3 = 0, s4 = 0;
    for (int k = lane; k < 512; k += 64) {
      const double* p = partials + (size_t)k * 5;
      s0 += p[0]; s1 += p[1]; s2 += p[2]; s3 += p[3]; s4 += p[4];
    }
    for (int off = 32; off > 0; off >>= 1) {
      s0 += __shfl_down(s0, off); s1 += __shfl_down(s1, off);
      s2 += __shfl_down(s2, off); s3 += __shfl_down(s3, off);
      s4 += __shfl_down(s4, off);
    }
    if (lane == 0) {
      double mean = (s0 + s1 + s2 + s3) * 0.25;
      double var = ((s0 - mean) * (s0 - mean) + (s1 - mean) * (s1 - mean) +
                    (s2 - mean) * (s2 - mean) + (s3 - mean) * (s3 - mean)) * 0.25;
      out[16777216] = (float)(s4 / (double)NTOK);
      out[16777217] = (float)(var / (mean * mean + 1e-10));
    }
  }

  if (wg >= total) return;
  {
    const unsigned ti = wg;
    int e; unsigned pe, cnt;
    if (ti >= p3)      { e = 3; pe = p3; cnt = c3; }
    else if (ti >= p2) { e = 2; pe = p2; cnt = c2; }
    else if (ti >= p1) { e = 1; pe = p1; cnt = c1; }
    else               { e = 0; pe = 0;  cnt = c0; }
    const unsigned rows0 = (ti - pe) * 64u;
    const int mcnt = (int)min(64u, cnt - rows0);
    const size_t pbase = (size_t)e * NTOK + rows0;

    const unsigned tokr = perm[pbase + (unsigned)(lane < mcnt ? lane : (mcnt - 1))];
    const float gvr = gval[tokr];

    // stage Xs: thread -> row tid>>2, col-chunks c = i*4 + (tid&3), 8 f32 each
    {
      const int r = tid >> 2, q = tid & 3;
      const unsigned tokS = perm[pbase + (unsigned)(r < mcnt ? r : mcnt - 1)];
      const float* src = x + (size_t)tokS * DIN;
      const int rf = r >> 5, r31 = r & 31;
#pragma unroll
      for (int i = 0; i < 16; ++i) {
        const int c = i * 4 + q;
        const float4 f0 = *(const float4*)(src + c * 8);
        const float4 f1 = *(const float4*)(src + c * 8 + 4);
        const int k16 = c >> 1, kh = c & 1;
        const unsigned slot = ((unsigned)kh << 5) | ((unsigned)r31 ^ xorX(k16));
        *(short8*)(Xs + (((rf * 32 + k16) << 10) + (slot << 4))) = pack8(f0, f1);
      }
    }
    asm volatile("s_waitcnt lgkmcnt(0)" ::: "memory");
    __builtin_amdgcn_s_barrier();

    // acc2: 2 rf x 4 cf = 128 regs
    f32x16 acc2_00 = f32x16{}, acc2_01 = f32x16{}, acc2_02 = f32x16{}, acc2_03 = f32x16{};
    f32x16 acc2_10 = f32x16{}, acc2_11 = f32x16{}, acc2_12 = f32x16{}, acc2_13 = f32x16{};

    for (int c = 0; c < 8; ++c) {   // H-chunks of 128
      // ---- GEMM1: wave = 64r x 32c, k = 512, depth-4 B queue + 1-ahead A prefetch ----
      f32x16 acc1_0 = f32x16{}, acc1_1 = f32x16{};
      const char* pB1 = pw1 + (((size_t)((e * 32 + c * 4 + wid) * 32)) << 10) + ((size_t)lane << 4);
      short8 q0 = *(const short8*)(pB1);
      short8 q1 = *(const short8*)(pB1 + 1024);
      short8 q2 = *(const short8*)(pB1 + 2048);
      short8 q3 = *(const short8*)(pB1 + 3072);
      unsigned slc = ((unsigned)lh << 5) | ((unsigned)l31 ^ xorX(0));
      short8 a0c = *(const short8*)(Xs + (slc << 4));
      short8 a1c = *(const short8*)(Xs + ((32 << 10) + (slc << 4)));
#pragma unroll
      for (int kk = 0; kk < 32; ++kk) {
        short8 a0n, a1n;
        if (kk < 31) {
          const unsigned sn = ((unsigned)lh << 5) | ((unsigned)l31 ^ xorX(kk + 1));
          a0n = *(const short8*)(Xs + (((kk + 1) << 10) + (sn << 4)));
          a1n = *(const short8*)(Xs + (((33 + kk) << 10) + (sn << 4)));
        }
        short8 b;
        if ((kk & 3) == 0) b = q0; else if ((kk & 3) == 1) b = q1;
        else if ((kk & 3) == 2) b = q2; else b = q3;
        if (kk < 28) {
          const short8 nv = *(const short8*)(pB1 + ((size_t)(kk + 4) << 10));
          if ((kk & 3) == 0) q0 = nv; else if ((kk & 3) == 1) q1 = nv;
          else if ((kk & 3) == 2) q2 = nv; else q3 = nv;
        }
        __builtin_amdgcn_s_setprio(1);
        acc1_0 = mfma32(a0c, b, acc1_0);
        acc1_1 = mfma32(a1c, b, acc1_1);
        __builtin_amdgcn_s_setprio(0);
        a0c = a0n; a1c = a1n;
      }

      const float bias = b1[e * HID + c * 128 + wid * 32 + l31];

      // preload G2 kloc 0 frags for chunk c (4 streams; hidden under barrier)
      const char* p2_0 = pw2 + ((((size_t)(e * 16 + wid * 4) * 64) + c * 8) << 10) + ((size_t)lane << 4);
      const char* p2_1 = p2_0 + ((size_t)64 << 10);
      const char* p2_2 = p2_0 + ((size_t)128 << 10);
      const char* p2_3 = p2_0 + ((size_t)192 << 10);
      short8 cb0 = *(const short8*)(p2_0);
      short8 cb1 = *(const short8*)(p2_1);
      short8 cb2 = *(const short8*)(p2_2);
      short8 cb3 = *(const short8*)(p2_3);

      __builtin_amdgcn_s_barrier();   // all waves done reading Hs (prev chunk)

      // ---- bias + relu -> Hs (chunk 128, frag layout: unit = kloc*2+rf) ----
      {
        const int cloc = wid * 32 + l31;          // 0..127
        const int kloc = cloc >> 4, kh = (cloc >> 3) & 1;
        const unsigned cbyte = (unsigned)((cloc & 7) << 1);
#pragma unroll
        for (int rf = 0; rf < 2; ++rf) {
          const f32x16 av = rf ? acc1_1 : acc1_0;
#pragma unroll
          for (int v = 0; v < 16; ++v) {
            const int R31 = (v & 3) + 8 * (v >> 2) + 4 * lh;
            float val = av[v] + bias;
            val = val > 0.f ? val : 0.f;
            const unsigned slot = ((unsigned)kh << 5) | ((unsigned)R31 ^ xorX(kloc));
            *(unsigned short*)(Hs + (((kloc << 1) + rf) << 10) + (slot << 4) + cbyte) = f2bf(val);
          }
        }
      }
      asm volatile("s_waitcnt lgkmcnt(0)" ::: "memory");
      __builtin_amdgcn_s_barrier();

      // ---- GEMM2: wave = 64r x 128d (4 streams), k-chunk 128, 8 MFMA/iter + 1-ahead H prefetch ----
      unsigned sg = ((unsigned)lh << 5) | ((unsigned)l31 ^ xorX(0));
      short8 h0c = *(const short8*)(Hs + (sg << 4));
      short8 h1c = *(const short8*)(Hs + ((1 << 10) + (sg << 4)));
#pragma unroll
      for (int kloc = 0; kloc < 8; ++kloc) {
        short8 h0n, h1n, n0, n1, n2, n3;
        if (kloc < 7) {
          const unsigned sn = ((unsigned)lh << 5) | ((unsigned)l31 ^ xorX(kloc + 1));
          h0n = *(const short8*)(Hs + ((((kloc + 1) << 1) + 0) << 10) + (sn << 4));
          h1n = *(const short8*)(Hs + ((((kloc + 1) << 1) + 1) << 10) + (sn << 4));
          n0 = *(const short8*)(p2_0 + ((size_t)(kloc + 1) << 10));
          n1 = *(const short8*)(p2_1 + ((size_t)(kloc + 1) << 10));
          n2 = *(const short8*)(p2_2 + ((size_t)(kloc + 1) << 10));
          n3 = *(const short8*)(p2_3 + ((size_t)(kloc + 1) << 10));
        }
        __builtin_amdgcn_s_setprio(1);
        acc2_00 = mfma32(h0c, cb0, acc2_00);  acc2_10 = mfma32(h1c, cb0, acc2_10);
        acc2_01 = mfma32(h0c, cb1, acc2_01);  acc2_11 = mfma32(h1c, cb1, acc2_11);
        acc2_02 = mfma32(h0c, cb2, acc2_02);  acc2_12 = mfma32(h1c, cb2, acc2_12);
        acc2_03 = mfma32(h0c, cb3, acc2_03);  acc2_13 = mfma32(h1c, cb3, acc2_13);
        __builtin_amdgcn_s_setprio(0);
        if (kloc < 7) { h0c = h0n; h1c = h1n; cb0 = n0; cb1 = n1; cb2 = n2; cb3 = n3; }
      }
    }

    // ---- epilogue: (y + b2) * gate -> out ----
    const int dbase = wid * 128 + l31;
    const float bv0 = b2[e * DIN + dbase];
    const float bv1 = b2[e * DIN + dbase + 32];
    const float bv2 = b2[e * DIN + dbase + 64];
    const float bv3 = b2[e * DIN + dbase + 96];
#pragma unroll
    for (int rf = 0; rf < 2; ++rf) {
      const f32x16 y0 = rf ? acc2_10 : acc2_00;
      const f32x16 y1 = rf ? acc2_11 : acc2_01;
      const f32x16 y2 = rf ? acc2_12 : acc2_02;
      const f32x16 y3 = rf ? acc2_13 : acc2_03;
#pragma unroll
      for (int v = 0; v < 16; ++v) {
        const int R = rf * 32 + (v & 3) + 8 * (v >> 2) + 4 * lh;
        const unsigned tk = (unsigned)__shfl((int)tokr, R);
        const float gv = __shfl(gvr, R);
        if (R < mcnt) {
          float* orow = out + (size_t)tk * DIN + dbase;
          orow[0]  = (y0[v] + bv0) * gv;
          orow[32] = (y1[v] + bv1) * gv;
          orow[64] = (y2[v] + bv2) * gv;
          orow[96] = (y3[v] + bv3) * gv;
        }
      }
    }
  }
}

extern "C" void kernel_launch(void* const* d_in, const int* in_sizes, int n_in,
                              void* d_out, int out_size, void* d_ws, size_t ws_size,
                              hipStream_t stream) {
  const float* x   = (const float*)d_in[0];
  const float* emb = (const float*)d_in[1];
  const float* rw  = (const float*)d_in[2];
  const float* w1  = (const float*)d_in[3];
  const float* b1  = (const float*)d_in[4];
  const float* w2  = (const float*)d_in[5];
  const float* b2  = (const float*)d_in[6];
  float* out = (float*)d_out;

  char* ws = (char*)d_ws;
  unsigned* counts = (unsigned*)(ws + OFF_COUNTS);
  float* gval = (float*)(ws + OFF_GVAL);
  unsigned* perm = (unsigned*)(ws + OFF_PERM);
  double* partials = (double*)(ws + OFF_PART);
  char* pw1 = ws + OFF_WB1;
  char* pw2 = ws + OFF_WB2;

  hipMemsetAsync(ws, 0, 256, stream);
  router_kernel<<<512, 256, 0, stream>>>(x, emb, rw, gval, counts, perm, partials,
                                         w1, w2, pw1, pw2);

  hipFuncSetAttribute((const void*)ffn_kernel, hipFuncAttributeMaxDynamicSharedMemorySize, LDS_TOTAL);
  ffn_kernel<<<516, 256, LDS_TOTAL, stream>>>(x, b1, b2, pw1, pw2, counts, perm, gval, partials, out);
}